// Round 13
// baseline (358.706 us; speedup 1.0000x reference)
//
#include <hip/hip_runtime.h>
#include <hip/hip_bf16.h>
#include <stdint.h>

typedef unsigned short u16;
typedef __bf16 bf16x8 __attribute__((ext_vector_type(8)));
typedef __bf16 bf16x4 __attribute__((ext_vector_type(4)));
typedef float f32x4 __attribute__((ext_vector_type(4)));

#define BB 4
#define TT 2048
#define CC 1024
#define HH 16
#define DD 64

// 0.125 * log2(e): folded into Q so softmax runs in base-2 (exp2 = 1 instr).
#define QSCALE 0.18033688011112042f

__device__ __forceinline__ u16 f2bf(float f) {
  union { float f; unsigned int u; } v; v.f = f;
  unsigned int u = v.u;
  unsigned int r = (u + 0x7fffu + ((u >> 16) & 1u)) >> 16;
  return (u16)r;
}

__device__ __forceinline__ void async_copy16(const void* g, void* l) {
  __builtin_amdgcn_global_load_lds(
      (const __attribute__((address_space(1))) void*)g,
      (__attribute__((address_space(3))) void*)l, 16, 0, 0);
}

// -------- fused prep: z=0..3 transpose+cast weights, z=4..11 cast x --------
__global__ __launch_bounds__(256) void k_prep(
    const float* __restrict__ x, u16* __restrict__ xb,
    const float* __restrict__ w0, const float* __restrict__ w1,
    const float* __restrict__ w2, const float* __restrict__ w3,
    u16* __restrict__ t0, u16* __restrict__ t1,
    u16* __restrict__ t2, u16* __restrict__ t3) {
  int z = blockIdx.z;
  int tx = threadIdx.x, ty = threadIdx.y;
  if (z < 4) {
    const float* w = z == 0 ? w0 : z == 1 ? w1 : z == 2 ? w2 : w3;
    u16* t = z == 0 ? t0 : z == 1 ? t1 : z == 2 ? t2 : t3;
    __shared__ u16 tile[32][33];
    int k0 = blockIdx.x * 32, n0 = blockIdx.y * 32;
#pragma unroll
    for (int r = 0; r < 4; r++)
      tile[ty + r * 8][tx] = f2bf(w[(size_t)(k0 + ty + r * 8) * CC + n0 + tx]);
    __syncthreads();
#pragma unroll
    for (int r = 0; r < 4; r++)
      t[(size_t)(n0 + ty + r * 8) * CC + k0 + tx] = tile[tx][ty + r * 8];
  } else {
    int bid = (z - 4) * 1024 + blockIdx.y * 32 + blockIdx.x;
    int tid = ty * 32 + tx;
    int i = (bid * 256 + tid) * 4;
    float4 f = *reinterpret_cast<const float4*>(x + i);
    ushort4 o;
    o.x = f2bf(f.x); o.y = f2bf(f.y); o.z = f2bf(f.z); o.w = f2bf(f.w);
    *reinterpret_cast<ushort4*>(xb + i) = o;
  }
}

// ------------- transpose V: out_v fp32 (B,H,T,D) -> vbt bf16 (B,H,D,T) -------------
__global__ __launch_bounds__(256) void k_transpose_v(
    const float* __restrict__ out_v, u16* __restrict__ vbt) {
  int tb = blockIdx.x * 64;
  int bh = blockIdx.y;
  const float* src = out_v + (size_t)bh * TT * DD;
  u16* dst = vbt + (size_t)bh * TT * DD;
  __shared__ u16 tile[64][65];
  int tid = threadIdx.x;
#pragma unroll
  for (int p = 0; p < 4; p++) {
    int c = p * 256 + tid;
    int t = c >> 4, d0 = (c & 15) * 4;
    float4 f = *reinterpret_cast<const float4*>(src + (size_t)(tb + t) * DD + d0);
    tile[t][d0 + 0] = f2bf(f.x);
    tile[t][d0 + 1] = f2bf(f.y);
    tile[t][d0 + 2] = f2bf(f.z);
    tile[t][d0 + 3] = f2bf(f.w);
  }
  __syncthreads();
#pragma unroll
  for (int p = 0; p < 2; p++) {
    int c = p * 256 + tid;
    int d = c >> 3, t0 = (c & 7) * 8;
    ushort4 lo, hi;
    lo.x = tile[t0 + 0][d]; lo.y = tile[t0 + 1][d];
    lo.z = tile[t0 + 2][d]; lo.w = tile[t0 + 3][d];
    hi.x = tile[t0 + 4][d]; hi.y = tile[t0 + 5][d];
    hi.z = tile[t0 + 6][d]; hi.w = tile[t0 + 7][d];
    u16* o = dst + (size_t)d * TT + tb + t0;
    *reinterpret_cast<ushort4*>(o) = lo;
    *reinterpret_cast<ushort4*>(o + 4) = hi;
  }
}

// ====== 8-phase-style GEMM core: BM=BN=256, BK=64, 512 thr (2x4 waves) ======
// Per-wave output 128x64 (acc[8][4]). LDS sA/sB[dbuf][khalf][256*32] u16,
// R9-proven slot swizzle (slot s of row r holds elems (s^((r>>1)&3))*8..+7;
// measured SQ_LDS_BANK_CONFLICT = 0). 4 phases per K-tile, each:
//   {vmcnt(4) at ph0/ph2} barrier | stage 1 granule of kt+1 | ds_read subtile
//   | lgkmcnt(0)+sched_barrier | setprio(1) 16 MFMA setprio(0)
// Counted vmcnt never drains mid-loop (drain only at kt=15). Granule order
// [A-kh0, B-kh0, A-kh1, B-kh1]; write-after-read separated by >=2 barriers.
#define MFMA16(AF, BF, ACCBASE)                                                \
  _Pragma("unroll")                                                            \
  for (int i = 0; i < 4; i++)                                                  \
    _Pragma("unroll")                                                          \
    for (int j = 0; j < 4; j++)                                                \
      acc[(ACCBASE) + i][j] = __builtin_amdgcn_mfma_f32_16x16x32_bf16(         \
          AF[i], BF[j], acc[(ACCBASE) + i][j], 0, 0, 0);

#define GEMM8_PROLOGUE()                                                       \
  int tid = threadIdx.x;                                                       \
  int lane = tid & 63;                                                         \
  int wave = tid >> 6;                                                         \
  int l15 = lane & 15, quad = lane >> 4;                                       \
  int wr = wave >> 2, wc = wave & 3;                                           \
  __shared__ u16 sA[2][2][256 * 32];                                           \
  __shared__ u16 sB[2][2][256 * 32];                                           \
  f32x4 acc[8][4] = {};                                                        \
  int g_r0 = tid >> 2, g_e0 = ((tid & 3) ^ ((tid >> 3) & 3)) * 8;              \
  int g_c1 = tid + 512;                                                        \
  int g_r1 = g_c1 >> 2, g_e1 = ((g_c1 & 3) ^ ((g_c1 >> 3) & 3)) * 8;           \
  auto stageA = [&](int d, int kh, int k0) {                                   \
    async_copy16(A + (size_t)(tile_m + g_r0) * CC + k0 + kh * 32 + g_e0,       \
                 &sA[d][kh][tid * 8]);                                         \
    async_copy16(A + (size_t)(tile_m + g_r1) * CC + k0 + kh * 32 + g_e1,       \
                 &sA[d][kh][g_c1 * 8]);                                        \
  };                                                                           \
  auto stageB = [&](int d, int kh, int k0) {                                   \
    async_copy16(Bt + (size_t)(tile_n + g_r0) * CC + k0 + kh * 32 + g_e0,      \
                 &sB[d][kh][tid * 8]);                                         \
    async_copy16(Bt + (size_t)(tile_n + g_r1) * CC + k0 + kh * 32 + g_e1,      \
                 &sB[d][kh][g_c1 * 8]);                                        \
  };                                                                           \
  int offA[8], offB[4];                                                        \
  _Pragma("unroll")                                                            \
  for (int mi = 0; mi < 8; mi++) {                                             \
    int RA = wr * 128 + mi * 16 + l15;                                         \
    offA[mi] = RA * 32 + (quad ^ ((RA >> 1) & 3)) * 8;                         \
  }                                                                            \
  _Pragma("unroll")                                                            \
  for (int j = 0; j < 4; j++) {                                                \
    int RB = wc * 64 + j * 16 + l15;                                           \
    offB[j] = RB * 32 + (quad ^ ((RB >> 1) & 3)) * 8;                          \
  }                                                                            \
  stageA(0, 0, 0); stageB(0, 0, 0); stageA(0, 1, 0); stageB(0, 1, 0);          \
  for (int kt = 0; kt < 16; kt++) {                                            \
    int d = kt & 1;                                                            \
    int kn = (kt + 1) * 64;                                                    \
    /* ---- phase 0: kh0, M-group 0 ---- */                                    \
    asm volatile("s_waitcnt vmcnt(4)" ::: "memory");                           \
    __builtin_amdgcn_sched_barrier(0);                                         \
    __builtin_amdgcn_s_barrier();                                              \
    __builtin_amdgcn_sched_barrier(0);                                         \
    if (kt < 15) stageA(d ^ 1, 0, kn);                                         \
    bf16x8 b0[4], af[4];                                                       \
    _Pragma("unroll")                                                          \
    for (int j = 0; j < 4; j++)                                                \
      b0[j] = *reinterpret_cast<const bf16x8*>(&sB[d][0][offB[j]]);            \
    _Pragma("unroll")                                                          \
    for (int i = 0; i < 4; i++)                                                \
      af[i] = *reinterpret_cast<const bf16x8*>(&sA[d][0][offA[i]]);            \
    asm volatile("s_waitcnt lgkmcnt(0)" ::: "memory");                         \
    __builtin_amdgcn_sched_barrier(0);                                         \
    __builtin_amdgcn_s_setprio(1);                                             \
    MFMA16(af, b0, 0)                                                          \
    __builtin_amdgcn_s_setprio(0);                                             \
    /* ---- phase 1: kh0, M-group 1 ---- */                                    \
    __builtin_amdgcn_sched_barrier(0);                                         \
    __builtin_amdgcn_s_barrier();                                              \
    __builtin_amdgcn_sched_barrier(0);                                         \
    if (kt < 15) stageB(d ^ 1, 0, kn);                                         \
    _Pragma("unroll")                                                          \
    for (int i = 0; i < 4; i++)                                                \
      af[i] = *reinterpret_cast<const bf16x8*>(&sA[d][0][offA[4 + i]]);        \
    asm volatile("s_waitcnt lgkmcnt(0)" ::: "memory");                         \
    __builtin_amdgcn_sched_barrier(0);                                         \
    __builtin_amdgcn_s_setprio(1);                                             \
    MFMA16(af, b0, 4)                                                          \
    __builtin_amdgcn_s_setprio(0);                                             \
    /* ---- phase 2: kh1, M-group 0 ---- */                                    \
    if (kt < 15)                                                               \
      asm volatile("s_waitcnt vmcnt(4)" ::: "memory");                         \
    else                                                                       \
      asm volatile("s_waitcnt vmcnt(0)" ::: "memory");                         \
    __builtin_amdgcn_sched_barrier(0);                                         \
    __builtin_amdgcn_s_barrier();                                              \
    __builtin_amdgcn_sched_barrier(0);                                         \
    if (kt < 15) stageA(d ^ 1, 1, kn);                                         \
    bf16x8 b1[4];                                                              \
    _Pragma("unroll")                                                          \
    for (int j = 0; j < 4; j++)                                                \
      b1[j] = *reinterpret_cast<const bf16x8*>(&sB[d][1][offB[j]]);            \
    _Pragma("unroll")                                                          \
    for (int i = 0; i < 4; i++)                                                \
      af[i] = *reinterpret_cast<const bf16x8*>(&sA[d][1][offA[i]]);            \
    asm volatile("s_waitcnt lgkmcnt(0)" ::: "memory");                         \
    __builtin_amdgcn_sched_barrier(0);                                         \
    __builtin_amdgcn_s_setprio(1);                                             \
    MFMA16(af, b1, 0)                                                          \
    __builtin_amdgcn_s_setprio(0);                                             \
    /* ---- phase 3: kh1, M-group 1 ---- */                                    \
    __builtin_amdgcn_sched_barrier(0);                                         \
    __builtin_amdgcn_s_barrier();                                              \
    __builtin_amdgcn_sched_barrier(0);                                         \
    if (kt < 15) stageB(d ^ 1, 1, kn);                                         \
    _Pragma("unroll")                                                          \
    for (int i = 0; i < 4; i++)                                                \
      af[i] = *reinterpret_cast<const bf16x8*>(&sA[d][1][offA[4 + i]]);        \
    asm volatile("s_waitcnt lgkmcnt(0)" ::: "memory");                         \
    __builtin_amdgcn_sched_barrier(0);                                         \
    __builtin_amdgcn_s_setprio(1);                                             \
    MFMA16(af, b1, 4)                                                          \
    __builtin_amdgcn_s_setprio(0);                                             \
  }

// ---------------- fused QKV GEMM ----------------
__global__ __launch_bounds__(512, 2) void k_gemm_qkv(
    const u16* __restrict__ xb,
    const u16* __restrict__ wtq, const u16* __restrict__ wtk, const u16* __restrict__ wtv,
    const float* __restrict__ bq, const float* __restrict__ bk, const float* __restrict__ bv,
    u16* __restrict__ qb, u16* __restrict__ kb,
    float* __restrict__ out_k, float* __restrict__ out_v) {
  int mat = blockIdx.z;
  const u16* A = xb;
  const u16* Bt = mat == 0 ? wtq : mat == 1 ? wtk : wtv;
  const float* bias = mat == 0 ? bq : mat == 1 ? bk : bv;
  int tile_m = blockIdx.x * 256;
  int tile_n = blockIdx.y * 256;

  GEMM8_PROLOGUE()

#pragma unroll
  for (int j = 0; j < 4; j++) {
    int n = tile_n + wc * 64 + j * 16 + l15;
    int h = n >> 6, dd = n & 63;
    float bias_n = bias[n];
#pragma unroll
    for (int mi = 0; mi < 8; mi++) {
#pragma unroll
      for (int r = 0; r < 4; r++) {
        int m = tile_m + wr * 128 + mi * 16 + quad * 4 + r;
        int b = m >> 11, t = m & 2047;
        float val = acc[mi][j][r] + bias_n;
        size_t idx = (((size_t)(b * HH + h)) * TT + t) * DD + dd;
        if (mat == 0) {
          qb[idx] = f2bf(val * QSCALE);
        } else if (mat == 1) {
          out_k[idx] = val;
          kb[idx] = f2bf(val);
        } else {
          out_v[idx] = val;
        }
      }
    }
  }
}

// ---------------- output projection ----------------
__global__ __launch_bounds__(512, 2) void k_gemm_proj(
    const u16* __restrict__ yb, const u16* __restrict__ wtp,
    const float* __restrict__ bp, float* __restrict__ out) {
  const u16* A = yb;
  const u16* Bt = wtp;
  int tile_m = blockIdx.x * 256;
  int tile_n = blockIdx.y * 256;

  GEMM8_PROLOGUE()

#pragma unroll
  for (int j = 0; j < 4; j++) {
    int n = tile_n + wc * 64 + j * 16 + l15;
    float bias_n = bp[n];
#pragma unroll
    for (int mi = 0; mi < 8; mi++) {
#pragma unroll
      for (int r = 0; r < 4; r++) {
        int m = tile_m + wr * 128 + mi * 16 + quad * 4 + r;
        out[(size_t)m * CC + n] = acc[mi][j][r] + bias_n;
      }
    }
  }
}

// ---------------- flash attention (causal), swapped QK^T (unchanged) ----------------
__global__ __launch_bounds__(256) void k_attn(
    const u16* __restrict__ qb, const u16* __restrict__ kbuf,
    const u16* __restrict__ vtb, u16* __restrict__ yatt) {
  int qpair = blockIdx.x;
  int bh = blockIdx.y;
  int tid = threadIdx.x;
  int lane = tid & 63;
  int wave = tid >> 6;
  int l15 = lane & 15, quad = lane >> 4;

  const u16* Q = qb + (size_t)bh * TT * DD;
  const u16* K = kbuf + (size_t)bh * TT * DD;
  const u16* Vt = vtb + (size_t)bh * TT * DD;  // [d][t]

  __shared__ u16 kl[2][64 * 64];
  __shared__ u16 vl[2][64 * 64];
  __shared__ u16 pl[4][16 * 64];
  u16* plw = pl[wave];

  int h = bh & 15, b = bh >> 4;

  int c0 = tid, c1 = tid + 256;
  int r0 = c0 >> 3, e0 = (((c0 & 7) * 16) ^ ((r0 & 7) << 4)) >> 1;
  int r1 = c1 >> 3, e1 = (((c1 & 7) * 16) ^ ((r1 & 7) << 4)) >> 1;

  auto stage = [&](int buf, int kb0) {
    async_copy16(K + (size_t)(kb0 + r0) * DD + e0, &kl[buf][c0 * 8]);
    async_copy16(K + (size_t)(kb0 + r1) * DD + e1, &kl[buf][c1 * 8]);
    async_copy16(Vt + (size_t)r0 * TT + kb0 + e0, &vl[buf][c0 * 8]);
    async_copy16(Vt + (size_t)r1 * TT + kb0 + e1, &vl[buf][c1 * 8]);
  };

  u16* prow = plw + l15 * 64;
  int xrp = (l15 & 7) << 4;
  int q8 = quad << 3;

#pragma unroll
  for (int side = 0; side < 2; side++) {
    int qt = side == 0 ? qpair : 31 - qpair;

    int qr = qt * 64 + wave * 16 + l15;
    bf16x8 qf0 = *reinterpret_cast<const bf16x8*>(Q + (size_t)qr * DD + quad * 8);
    bf16x8 qf1 = *reinterpret_cast<const bf16x8*>(Q + (size_t)qr * DD + 32 + quad * 8);

    f32x4 o_acc[4] = {};
    float m_run = -1e30f, l_run = 0.f;

    stage(0, 0);

    for (int kblk = 0; kblk <= qt; kblk++) {
      int cur = kblk & 1;
      if (kblk < qt) {
        stage(cur ^ 1, (kblk + 1) * 64);
        asm volatile("s_waitcnt vmcnt(4)" ::: "memory");
      } else {
        asm volatile("s_waitcnt vmcnt(0)" ::: "memory");
      }
      __builtin_amdgcn_sched_barrier(0);
      __builtin_amdgcn_s_barrier();
      __builtin_amdgcn_sched_barrier(0);

      f32x4 s_acc[4];
      __builtin_amdgcn_s_setprio(1);
#pragma unroll
      for (int nb = 0; nb < 4; nb++) {
        int krow = nb * 16 + l15;
        int xr = (krow & 7) << 4;
        const u16* kp = &kl[cur][krow * 64];
        bf16x8 kf0 = *reinterpret_cast<const bf16x8*>(kp + (((quad * 16) ^ xr) >> 1));
        bf16x8 kf1 = *reinterpret_cast<const bf16x8*>(kp + (((64 + quad * 16) ^ xr) >> 1));
        f32x4 z = {};
        z = __builtin_amdgcn_mfma_f32_16x16x32_bf16(kf0, qf0, z, 0, 0, 0);
        z = __builtin_amdgcn_mfma_f32_16x16x32_bf16(kf1, qf1, z, 0, 0, 0);
        s_acc[nb] = z;
      }
      __builtin_amdgcn_s_setprio(0);

      float mx = -1e30f;
      if (kblk == qt) {
        int qg = wave * 16 + l15;
#pragma unroll
        for (int nb = 0; nb < 4; nb++)
#pragma unroll
          for (int r = 0; r < 4; r++) {
            int kg = nb * 16 + quad * 4 + r;
            float s = s_acc[nb][r];
            s = (kg <= qg) ? s : -1e30f;
            s_acc[nb][r] = s;
            mx = fmaxf(mx, s);
          }
      } else {
#pragma unroll
        for (int nb = 0; nb < 4; nb++)
#pragma unroll
          for (int r = 0; r < 4; r++) mx = fmaxf(mx, s_acc[nb][r]);
      }
      mx = fmaxf(mx, __shfl_xor(mx, 16, 64));
      mx = fmaxf(mx, __shfl_xor(mx, 32, 64));

      if (!__all(mx - m_run <= 8.0f)) {
        float mnew = fmaxf(m_run, mx);
        float alpha = __builtin_amdgcn_exp2f(m_run - mnew);
        m_run = mnew;
        l_run *= alpha;
        float av[4];
#pragma unroll
        for (int r = 0; r < 4; r++) av[r] = __shfl(alpha, quad * 4 + r, 64);
#pragma unroll
        for (int db = 0; db < 4; db++)
#pragma unroll
          for (int r = 0; r < 4; r++) o_acc[db][r] *= av[r];
      }

      float sum = 0.f;
#pragma unroll
      for (int nb = 0; nb < 4; nb++)
#pragma unroll
        for (int r = 0; r < 4; r++) {
          float e = __builtin_amdgcn_exp2f(s_acc[nb][r] - m_run);
          s_acc[nb][r] = e;
          sum += e;
        }
      sum += __shfl_xor(sum, 16, 64);
      sum += __shfl_xor(sum, 32, 64);
      l_run += sum;

#pragma unroll
      for (int nb = 0; nb < 4; nb++) {
        bf16x4 pk = {(__bf16)s_acc[nb][0], (__bf16)s_acc[nb][1],
                     (__bf16)s_acc[nb][2], (__bf16)s_acc[nb][3]};
        *reinterpret_cast<bf16x4*>(prow + ((((nb << 5) + q8) ^ xrp) >> 1)) = pk;
      }

      __builtin_amdgcn_s_setprio(1);
#pragma unroll
      for (int half = 0; half < 2; half++) {
        bf16x8 pf = *reinterpret_cast<const bf16x8*>(
            prow + (((half * 64 + quad * 16) ^ xrp) >> 1));
#pragma unroll
        for (int db = 0; db < 4; db++) {
          int vrow = db * 16 + l15;
          bf16x8 vf = *reinterpret_cast<const bf16x8*>(
              &vl[cur][vrow * 64] + (((half * 64 + quad * 16) ^ ((vrow & 7) << 4)) >> 1));
          o_acc[db] = __builtin_amdgcn_mfma_f32_16x16x32_bf16(pf, vf, o_acc[db], 0, 0, 0);
        }
      }
      __builtin_amdgcn_s_setprio(0);

      __builtin_amdgcn_sched_barrier(0);
      __builtin_amdgcn_s_barrier();
    }

    float lr[4];
#pragma unroll
    for (int r = 0; r < 4; r++) lr[r] = __shfl(l_run, quad * 4 + r, 64);
#pragma unroll
    for (int r = 0; r < 4; r++) {
      float inv = 1.0f / lr[r];
      int tq = qt * 64 + wave * 16 + quad * 4 + r;
#pragma unroll
      for (int db = 0; db < 4; db++) {
        int d = db * 16 + l15;
        yatt[((size_t)(b * TT + tq)) * CC + h * DD + d] = f2bf(o_acc[db][r] * inv);
      }
    }
  }
}

extern "C" void kernel_launch(void* const* d_in, const int* in_sizes, int n_in,
                              void* d_out, int out_size, void* d_ws, size_t ws_size,
                              hipStream_t stream) {
  const float* x  = (const float*)d_in[0];
  const float* wq = (const float*)d_in[1];
  const float* bq = (const float*)d_in[2];
  const float* wk = (const float*)d_in[3];
  const float* bk = (const float*)d_in[4];
  const float* wv = (const float*)d_in[5];
  const float* bv = (const float*)d_in[6];
  const float* wp = (const float*)d_in[7];
  const float* bp = (const float*)d_in[8];

  float* out_y = (float*)d_out;                       // (B,T,C)
  float* out_k = out_y + (size_t)BB * TT * CC;        // (B,H,T,D)
  float* out_v = out_k + (size_t)BB * HH * TT * DD;   // (B,H,T,D)

  u16* xb  = (u16*)d_ws;                    // B*T*C
  u16* wtq = xb + (size_t)BB * TT * CC;
  u16* wtk = wtq + (size_t)CC * CC;
  u16* wtv = wtk + (size_t)CC * CC;
  u16* wtp = wtv + (size_t)CC * CC;
  u16* qb  = wtp + (size_t)CC * CC;         // (B,H,T,D) bf16, pre-scaled QSCALE
  u16* kb  = qb + (size_t)BB * TT * CC;     // (B,H,T,D) bf16
  u16* vbt = kb + (size_t)BB * TT * CC;     // (B,H,D,T) bf16
  u16* yb  = vbt + (size_t)BB * TT * CC;    // (B,T,C) bf16

  k_prep<<<dim3(32, 32, 12), dim3(32, 8), 0, stream>>>(
      x, xb, wq, wk, wv, wp, wtq, wtk, wtv, wtp);
  k_gemm_qkv<<<dim3(BB * TT / 256, CC / 256, 3), 512, 0, stream>>>(
      xb, wtq, wtk, wtv, bq, bk, bv, qb, kb, out_k, out_v);
  k_transpose_v<<<dim3(TT / 64, BB * HH), 256, 0, stream>>>(out_v, vbt);
  k_attn<<<dim3(16, BB * HH), 256, 0, stream>>>(qb, kb, vbt, yb);
  k_gemm_proj<<<dim3(BB * TT / 256, CC / 256), 512, 0, stream>>>(yb, wtp, bp, out_y);
}

// Round 14
// 338.624 us; speedup vs baseline: 1.0593x; 1.0593x over previous
//
#include <hip/hip_runtime.h>
#include <hip/hip_bf16.h>
#include <stdint.h>

typedef unsigned short u16;
typedef __bf16 bf16x8 __attribute__((ext_vector_type(8)));
typedef __bf16 bf16x4 __attribute__((ext_vector_type(4)));
typedef float f32x4 __attribute__((ext_vector_type(4)));

#define BB 4
#define TT 2048
#define CC 1024
#define HH 16
#define DD 64

// 0.125 * log2(e): folded into Q so softmax runs in base-2 (exp2 = 1 instr).
#define QSCALE 0.18033688011112042f

__device__ __forceinline__ u16 f2bf(float f) {
  union { float f; unsigned int u; } v; v.f = f;
  unsigned int u = v.u;
  unsigned int r = (u + 0x7fffu + ((u >> 16) & 1u)) >> 16;
  return (u16)r;
}

__device__ __forceinline__ void async_copy16(const void* g, void* l) {
  __builtin_amdgcn_global_load_lds(
      (const __attribute__((address_space(1))) void*)g,
      (__attribute__((address_space(3))) void*)l, 16, 0, 0);
}

// -------- fused prep: z=0..3 transpose+cast weights, z=4..11 cast x --------
__global__ __launch_bounds__(256) void k_prep(
    const float* __restrict__ x, u16* __restrict__ xb,
    const float* __restrict__ w0, const float* __restrict__ w1,
    const float* __restrict__ w2, const float* __restrict__ w3,
    u16* __restrict__ t0, u16* __restrict__ t1,
    u16* __restrict__ t2, u16* __restrict__ t3) {
  int z = blockIdx.z;
  int tx = threadIdx.x, ty = threadIdx.y;
  if (z < 4) {
    const float* w = z == 0 ? w0 : z == 1 ? w1 : z == 2 ? w2 : w3;
    u16* t = z == 0 ? t0 : z == 1 ? t1 : z == 2 ? t2 : t3;
    __shared__ u16 tile[32][33];
    int k0 = blockIdx.x * 32, n0 = blockIdx.y * 32;
#pragma unroll
    for (int r = 0; r < 4; r++)
      tile[ty + r * 8][tx] = f2bf(w[(size_t)(k0 + ty + r * 8) * CC + n0 + tx]);
    __syncthreads();
#pragma unroll
    for (int r = 0; r < 4; r++)
      t[(size_t)(n0 + ty + r * 8) * CC + k0 + tx] = tile[tx][ty + r * 8];
  } else {
    int bid = (z - 4) * 1024 + blockIdx.y * 32 + blockIdx.x;
    int tid = ty * 32 + tx;
    int i = (bid * 256 + tid) * 4;
    float4 f = *reinterpret_cast<const float4*>(x + i);
    ushort4 o;
    o.x = f2bf(f.x); o.y = f2bf(f.y); o.z = f2bf(f.z); o.w = f2bf(f.w);
    *reinterpret_cast<ushort4*>(xb + i) = o;
  }
}

// ------------- transpose V: out_v fp32 (B,H,T,D) -> vbt bf16 (B,H,D,T) -------------
__global__ __launch_bounds__(256) void k_transpose_v(
    const float* __restrict__ out_v, u16* __restrict__ vbt) {
  int tb = blockIdx.x * 64;
  int bh = blockIdx.y;
  const float* src = out_v + (size_t)bh * TT * DD;
  u16* dst = vbt + (size_t)bh * TT * DD;
  __shared__ u16 tile[64][65];
  int tid = threadIdx.x;
#pragma unroll
  for (int p = 0; p < 4; p++) {
    int c = p * 256 + tid;
    int t = c >> 4, d0 = (c & 15) * 4;
    float4 f = *reinterpret_cast<const float4*>(src + (size_t)(tb + t) * DD + d0);
    tile[t][d0 + 0] = f2bf(f.x);
    tile[t][d0 + 1] = f2bf(f.y);
    tile[t][d0 + 2] = f2bf(f.z);
    tile[t][d0 + 3] = f2bf(f.w);
  }
  __syncthreads();
#pragma unroll
  for (int p = 0; p < 2; p++) {
    int c = p * 256 + tid;
    int d = c >> 3, t0 = (c & 7) * 8;
    ushort4 lo, hi;
    lo.x = tile[t0 + 0][d]; lo.y = tile[t0 + 1][d];
    lo.z = tile[t0 + 2][d]; lo.w = tile[t0 + 3][d];
    hi.x = tile[t0 + 4][d]; hi.y = tile[t0 + 5][d];
    hi.z = tile[t0 + 6][d]; hi.w = tile[t0 + 7][d];
    u16* o = dst + (size_t)d * TT + tb + t0;
    *reinterpret_cast<ushort4*>(o) = lo;
    *reinterpret_cast<ushort4*>(o + 4) = hi;
  }
}

// ---------------- GEMM core (R10, best measured): ring-3, 2-deep prefetch ----------------
// LDS tile [128][32] u16 (64B rows), 16B slot s of row r at linear slot
// r*4 + (s ^ ((r>>1)&3)) (R9-verified: SQ_LDS_BANK_CONFLICT = 0).
// Stage tile ks+2 at iter ks (ring-3). vmcnt(8) leaves tiles ks+1, ks+2 in
// flight and guarantees tile ks landed. Tail: vmcnt(4), vmcnt(0).
#define GEMM_PROLOGUE()                                                        \
  int tid = threadIdx.x;                                                       \
  int lane = tid & 63;                                                         \
  int wave = tid >> 6;                                                         \
  int l15 = lane & 15, quad = lane >> 4;                                       \
  int wave_m = wave & 1, wave_n = wave >> 1;                                   \
  __shared__ u16 lA[3][128 * 32];                                              \
  __shared__ u16 lB[3][128 * 32];                                              \
  f32x4 acc[4][4] = {};                                                        \
  int s_c0 = tid, s_c1 = tid + 256;                                            \
  int s_r0 = s_c0 >> 2, s_e0 = ((s_c0 & 3) ^ ((s_c0 >> 3) & 3)) * 8;           \
  int s_r1 = s_c1 >> 2, s_e1 = ((s_c1 & 3) ^ ((s_c1 >> 3) & 3)) * 8;           \
  auto gstage = [&](int buf, int k0) {                                         \
    async_copy16(A + (size_t)(tile_m + s_r0) * CC + k0 + s_e0,                 \
                 &lA[buf][s_c0 * 8]);                                          \
    async_copy16(A + (size_t)(tile_m + s_r1) * CC + k0 + s_e1,                 \
                 &lA[buf][s_c1 * 8]);                                          \
    async_copy16(Bt + (size_t)(tile_n + s_r0) * CC + k0 + s_e0,                \
                 &lB[buf][s_c0 * 8]);                                          \
    async_copy16(Bt + (size_t)(tile_n + s_r1) * CC + k0 + s_e1,                \
                 &lB[buf][s_c1 * 8]);                                          \
  };                                                                           \
  int offA[4], offB[4];                                                        \
  _Pragma("unroll")                                                            \
  for (int i = 0; i < 4; i++) {                                                \
    int rA = wave_m * 64 + i * 16 + l15;                                       \
    offA[i] = rA * 32 + (quad ^ ((rA >> 1) & 3)) * 8;                          \
    int rB = wave_n * 64 + i * 16 + l15;                                       \
    offB[i] = rB * 32 + (quad ^ ((rB >> 1) & 3)) * 8;                          \
  }                                                                            \
  gstage(0, 0);                                                                \
  gstage(1, 32);                                                               \
  int curb = 0;                                                                \
  for (int ks = 0; ks < CC / 32; ks++) {                                       \
    int nxt = curb + 2; nxt = (nxt >= 3) ? nxt - 3 : nxt;                      \
    if (ks < CC / 32 - 2) {                                                    \
      gstage(nxt, (ks + 2) * 32);                                              \
      asm volatile("s_waitcnt vmcnt(8)" ::: "memory");                         \
    } else if (ks == CC / 32 - 2) {                                            \
      asm volatile("s_waitcnt vmcnt(4)" ::: "memory");                         \
    } else {                                                                   \
      asm volatile("s_waitcnt vmcnt(0)" ::: "memory");                         \
    }                                                                          \
    __builtin_amdgcn_sched_barrier(0);                                         \
    __builtin_amdgcn_s_barrier();                                              \
    __builtin_amdgcn_sched_barrier(0);                                         \
    bf16x8 af[4], bfr[4];                                                      \
    _Pragma("unroll")                                                          \
    for (int i = 0; i < 4; i++)                                                \
      af[i] = *reinterpret_cast<const bf16x8*>(&lA[curb][offA[i]]);            \
    _Pragma("unroll")                                                          \
    for (int j = 0; j < 4; j++)                                                \
      bfr[j] = *reinterpret_cast<const bf16x8*>(&lB[curb][offB[j]]);           \
    __builtin_amdgcn_s_setprio(1);                                             \
    _Pragma("unroll")                                                          \
    for (int i = 0; i < 4; i++)                                                \
      _Pragma("unroll")                                                        \
      for (int j = 0; j < 4; j++)                                              \
        acc[i][j] =                                                            \
            __builtin_amdgcn_mfma_f32_16x16x32_bf16(af[i], bfr[j], acc[i][j],  \
                                                    0, 0, 0);                  \
    __builtin_amdgcn_s_setprio(0);                                             \
    __builtin_amdgcn_sched_barrier(0);                                         \
    __builtin_amdgcn_s_barrier();                                              \
    curb = (curb == 2) ? 0 : curb + 1;                                         \
  }

// ---------------- fused QKV GEMM ----------------
// NOTE: Q output is pre-scaled by 0.125*log2(e) so the attention kernel runs
// softmax in base-2 with no per-element scaling.
__global__ __launch_bounds__(256) void k_gemm_qkv(
    const u16* __restrict__ xb,
    const u16* __restrict__ wtq, const u16* __restrict__ wtk, const u16* __restrict__ wtv,
    const float* __restrict__ bq, const float* __restrict__ bk, const float* __restrict__ bv,
    u16* __restrict__ qb, u16* __restrict__ kb,
    float* __restrict__ out_k, float* __restrict__ out_v) {
  int mat = blockIdx.z;
  const u16* A = xb;
  const u16* Bt = mat == 0 ? wtq : mat == 1 ? wtk : wtv;
  const float* bias = mat == 0 ? bq : mat == 1 ? bk : bv;
  int tile_m = blockIdx.x * 128;
  int tile_n = blockIdx.y * 128;

  GEMM_PROLOGUE()

#pragma unroll
  for (int j = 0; j < 4; j++) {
    int n = tile_n + wave_n * 64 + j * 16 + l15;
    int h = n >> 6, d = n & 63;
    float bias_n = bias[n];
#pragma unroll
    for (int i = 0; i < 4; i++) {
#pragma unroll
      for (int r = 0; r < 4; r++) {
        int m = tile_m + wave_m * 64 + i * 16 + quad * 4 + r;
        int b = m >> 11, t = m & 2047;
        float val = acc[i][j][r] + bias_n;
        size_t idx = (((size_t)(b * HH + h)) * TT + t) * DD + d;
        if (mat == 0) {
          qb[idx] = f2bf(val * QSCALE);
        } else if (mat == 1) {
          out_k[idx] = val;
          kb[idx] = f2bf(val);
        } else {
          out_v[idx] = val;
        }
      }
    }
  }
}

// ---------------- output projection ----------------
__global__ __launch_bounds__(256) void k_gemm_proj(
    const u16* __restrict__ yb, const u16* __restrict__ wtp,
    const float* __restrict__ bp, float* __restrict__ out) {
  const u16* A = yb;
  const u16* Bt = wtp;
  int tile_m = blockIdx.x * 128;
  int tile_n = blockIdx.y * 128;

  GEMM_PROLOGUE()

#pragma unroll
  for (int j = 0; j < 4; j++) {
    int n = tile_n + wave_n * 64 + j * 16 + l15;
    float bias_n = bp[n];
#pragma unroll
    for (int i = 0; i < 4; i++) {
#pragma unroll
      for (int r = 0; r < 4; r++) {
        int m = tile_m + wave_m * 64 + i * 16 + quad * 4 + r;
        out[(size_t)m * CC + n] = acc[i][j][r] + bias_n;
      }
    }
  }
}

// ---------------- flash attention (causal), swapped QK^T ----------------
// R2-verified conflict-free LDS geometry (all rows 128B stride, 40 KiB).
// QK^T computed as mfma(K, Q) -> S^T: each lane owns ONE q-row (l15) with
// 16 lane-local keys (nb*16 + quad*4 + r). Row max/sum = lane-local chain +
// 2 shuffles (xor 16, 32). m_run/l_run scalar; defer-max THR=8 (log2).
__global__ __launch_bounds__(256) void k_attn(
    const u16* __restrict__ qb, const u16* __restrict__ kbuf,
    const u16* __restrict__ vtb, u16* __restrict__ yatt) {
  int qpair = blockIdx.x;
  int bh = blockIdx.y;
  int tid = threadIdx.x;
  int lane = tid & 63;
  int wave = tid >> 6;
  int l15 = lane & 15, quad = lane >> 4;

  const u16* Q = qb + (size_t)bh * TT * DD;
  const u16* K = kbuf + (size_t)bh * TT * DD;
  const u16* Vt = vtb + (size_t)bh * TT * DD;  // [d][t]

  __shared__ u16 kl[2][64 * 64];   // swizzled [key][d], row stride 128 B
  __shared__ u16 vl[2][64 * 64];   // swizzled [d][t], row stride 128 B
  __shared__ u16 pl[4][16 * 64];   // per-wave P tile [qrow][key], swizzled
  u16* plw = pl[wave];

  int h = bh & 15, b = bh >> 4;

  int c0 = tid, c1 = tid + 256;
  int r0 = c0 >> 3, e0 = (((c0 & 7) * 16) ^ ((r0 & 7) << 4)) >> 1;
  int r1 = c1 >> 3, e1 = (((c1 & 7) * 16) ^ ((r1 & 7) << 4)) >> 1;

  auto stage = [&](int buf, int kb0) {
    async_copy16(K + (size_t)(kb0 + r0) * DD + e0, &kl[buf][c0 * 8]);
    async_copy16(K + (size_t)(kb0 + r1) * DD + e1, &kl[buf][c1 * 8]);
    async_copy16(Vt + (size_t)r0 * TT + kb0 + e0, &vl[buf][c0 * 8]);
    async_copy16(Vt + (size_t)r1 * TT + kb0 + e1, &vl[buf][c1 * 8]);
  };

  // P-write addressing (per-lane constants)
  u16* prow = plw + l15 * 64;          // this lane's q-row base
  int xrp = (l15 & 7) << 4;            // byte XOR for this row
  int q8 = quad << 3;                  // 4 contiguous keys = 8 bytes

#pragma unroll
  for (int side = 0; side < 2; side++) {
    int qt = side == 0 ? qpair : 31 - qpair;

    int qr = qt * 64 + wave * 16 + l15;
    bf16x8 qf0 = *reinterpret_cast<const bf16x8*>(Q + (size_t)qr * DD + quad * 8);
    bf16x8 qf1 = *reinterpret_cast<const bf16x8*>(Q + (size_t)qr * DD + 32 + quad * 8);

    f32x4 o_acc[4] = {};
    float m_run = -1e30f, l_run = 0.f;

    stage(0, 0);  // prologue: tile 0 into buffer 0 (4 loads/thread in flight)

    for (int kblk = 0; kblk <= qt; kblk++) {
      int cur = kblk & 1;
      if (kblk < qt) {
        stage(cur ^ 1, (kblk + 1) * 64);          // prefetch next tile
        asm volatile("s_waitcnt vmcnt(4)" ::: "memory");  // cur tile landed, next stays in flight
      } else {
        asm volatile("s_waitcnt vmcnt(0)" ::: "memory");  // last tile: drain
      }
      __builtin_amdgcn_sched_barrier(0);
      __builtin_amdgcn_s_barrier();
      __builtin_amdgcn_sched_barrier(0);

      // ---- S^T = K Q^T (64 keys x 16 qrows per wave), K from swizzled LDS ----
      f32x4 s_acc[4];
      __builtin_amdgcn_s_setprio(1);
#pragma unroll
      for (int nb = 0; nb < 4; nb++) {
        int krow = nb * 16 + l15;
        int xr = (krow & 7) << 4;
        const u16* kp = &kl[cur][krow * 64];
        bf16x8 kf0 = *reinterpret_cast<const bf16x8*>(kp + (((quad * 16) ^ xr) >> 1));
        bf16x8 kf1 = *reinterpret_cast<const bf16x8*>(kp + (((64 + quad * 16) ^ xr) >> 1));
        f32x4 z = {};
        z = __builtin_amdgcn_mfma_f32_16x16x32_bf16(kf0, qf0, z, 0, 0, 0);
        z = __builtin_amdgcn_mfma_f32_16x16x32_bf16(kf1, qf1, z, 0, 0, 0);
        s_acc[nb] = z;
      }
      __builtin_amdgcn_s_setprio(0);

      // ---- mask (diag block) + lane-local row max ----
      float mx = -1e30f;
      if (kblk == qt) {
        int qg = wave * 16 + l15;  // q offset within the 64-tile
#pragma unroll
        for (int nb = 0; nb < 4; nb++)
#pragma unroll
          for (int r = 0; r < 4; r++) {
            int kg = nb * 16 + quad * 4 + r;
            float s = s_acc[nb][r];
            s = (kg <= qg) ? s : -1e30f;
            s_acc[nb][r] = s;
            mx = fmaxf(mx, s);
          }
      } else {
#pragma unroll
        for (int nb = 0; nb < 4; nb++)
#pragma unroll
          for (int r = 0; r < 4; r++) mx = fmaxf(mx, s_acc[nb][r]);
      }
      mx = fmaxf(mx, __shfl_xor(mx, 16, 64));
      mx = fmaxf(mx, __shfl_xor(mx, 32, 64));

      // ---- defer-max: rescale only when running max grows by > 8 (log2) ----
      if (!__all(mx - m_run <= 8.0f)) {
        float mnew = fmaxf(m_run, mx);
        float alpha = __builtin_amdgcn_exp2f(m_run - mnew);
        m_run = mnew;
        l_run *= alpha;
        float av[4];
#pragma unroll
        for (int r = 0; r < 4; r++) av[r] = __shfl(alpha, quad * 4 + r, 64);
#pragma unroll
        for (int db = 0; db < 4; db++)
#pragma unroll
          for (int r = 0; r < 4; r++) o_acc[db][r] *= av[r];
      }

      // ---- exp2 + lane-local row sum (P bounded by 2^8 when deferred) ----
      float sum = 0.f;
#pragma unroll
      for (int nb = 0; nb < 4; nb++)
#pragma unroll
        for (int r = 0; r < 4; r++) {
          float e = __builtin_amdgcn_exp2f(s_acc[nb][r] - m_run);
          s_acc[nb][r] = e;
          sum += e;
        }
      sum += __shfl_xor(sum, 16, 64);
      sum += __shfl_xor(sum, 32, 64);
      l_run += sum;

      // ---- P[qrow=l15][key]: 4 contiguous keys -> one 8B store ----
#pragma unroll
      for (int nb = 0; nb < 4; nb++) {
        bf16x4 pk = {(__bf16)s_acc[nb][0], (__bf16)s_acc[nb][1],
                     (__bf16)s_acc[nb][2], (__bf16)s_acc[nb][3]};
        *reinterpret_cast<bf16x4*>(prow + ((((nb << 5) + q8) ^ xrp) >> 1)) = pk;
      }

      // ---- O += P V  (V^T from swizzled LDS) ----
      __builtin_amdgcn_s_setprio(1);
#pragma unroll
      for (int half = 0; half < 2; half++) {
        bf16x8 pf = *reinterpret_cast<const bf16x8*>(
            prow + (((half * 64 + quad * 16) ^ xrp) >> 1));
#pragma unroll
        for (int db = 0; db < 4; db++) {
          int vrow = db * 16 + l15;
          bf16x8 vf = *reinterpret_cast<const bf16x8*>(
              &vl[cur][vrow * 64] + (((half * 64 + quad * 16) ^ ((vrow & 7) << 4)) >> 1));
          o_acc[db] = __builtin_amdgcn_mfma_f32_16x16x32_bf16(pf, vf, o_acc[db], 0, 0, 0);
        }
      }
      __builtin_amdgcn_s_setprio(0);

      __builtin_amdgcn_sched_barrier(0);
      __builtin_amdgcn_s_barrier();   // all waves done reading buf cur before restage
    }

    // ---- epilogue: y_att[b][t][h*64+d] bf16 ----
    float lr[4];
#pragma unroll
    for (int r = 0; r < 4; r++) lr[r] = __shfl(l_run, quad * 4 + r, 64);
#pragma unroll
    for (int r = 0; r < 4; r++) {
      float inv = 1.0f / lr[r];
      int tq = qt * 64 + wave * 16 + quad * 4 + r;
#pragma unroll
      for (int db = 0; db < 4; db++) {
        int d = db * 16 + l15;
        yatt[((size_t)(b * TT + tq)) * CC + h * DD + d] = f2bf(o_acc[db][r] * inv);
      }
    }
  }
}

extern "C" void kernel_launch(void* const* d_in, const int* in_sizes, int n_in,
                              void* d_out, int out_size, void* d_ws, size_t ws_size,
                              hipStream_t stream) {
  const float* x  = (const float*)d_in[0];
  const float* wq = (const float*)d_in[1];
  const float* bq = (const float*)d_in[2];
  const float* wk = (const float*)d_in[3];
  const float* bk = (const float*)d_in[4];
  const float* wv = (const float*)d_in[5];
  const float* bv = (const float*)d_in[6];
  const float* wp = (const float*)d_in[7];
  const float* bp = (const float*)d_in[8];

  float* out_y = (float*)d_out;                       // (B,T,C)
  float* out_k = out_y + (size_t)BB * TT * CC;        // (B,H,T,D)
  float* out_v = out_k + (size_t)BB * HH * TT * DD;   // (B,H,T,D)

  u16* xb  = (u16*)d_ws;                    // B*T*C
  u16* wtq = xb + (size_t)BB * TT * CC;
  u16* wtk = wtq + (size_t)CC * CC;
  u16* wtv = wtk + (size_t)CC * CC;
  u16* wtp = wtv + (size_t)CC * CC;
  u16* qb  = wtp + (size_t)CC * CC;         // (B,H,T,D) bf16, pre-scaled QSCALE
  u16* kb  = qb + (size_t)BB * TT * CC;     // (B,H,T,D) bf16
  u16* vbt = kb + (size_t)BB * TT * CC;     // (B,H,D,T) bf16
  u16* yb  = vbt + (size_t)BB * TT * CC;    // (B,T,C) bf16

  k_prep<<<dim3(32, 32, 12), dim3(32, 8), 0, stream>>>(
      x, xb, wq, wk, wv, wp, wtq, wtk, wtv, wtp);
  k_gemm_qkv<<<dim3(BB * TT / 128, CC / 128, 3), 256, 0, stream>>>(
      xb, wtq, wtk, wtv, bq, bk, bv, qb, kb, out_k, out_v);
  k_transpose_v<<<dim3(TT / 64, BB * HH), 256, 0, stream>>>(out_v, vbt);
  k_attn<<<dim3(16, BB * HH), 256, 0, stream>>>(qb, kb, vbt, yb);
  k_gemm_proj<<<dim3(BB * TT / 128, CC / 128), 256, 0, stream>>>(yb, wtp, bp, out_y);
}

// Round 15
// 325.218 us; speedup vs baseline: 1.1030x; 1.0412x over previous
//
#include <hip/hip_runtime.h>
#include <hip/hip_bf16.h>
#include <stdint.h>

typedef unsigned short u16;
typedef __bf16 bf16x8 __attribute__((ext_vector_type(8)));
typedef __bf16 bf16x4 __attribute__((ext_vector_type(4)));
typedef float f32x4 __attribute__((ext_vector_type(4)));

#define BB 4
#define TT 2048
#define CC 1024
#define HH 16
#define DD 64

// 0.125 * log2(e): folded into Q so softmax runs in base-2 (exp2 = 1 instr).
#define QSCALE 0.18033688011112042f

__device__ __forceinline__ u16 f2bf(float f) {
  union { float f; unsigned int u; } v; v.f = f;
  unsigned int u = v.u;
  unsigned int r = (u + 0x7fffu + ((u >> 16) & 1u)) >> 16;
  return (u16)r;
}

__device__ __forceinline__ void async_copy16(const void* g, void* l) {
  __builtin_amdgcn_global_load_lds(
      (const __attribute__((address_space(1))) void*)g,
      (__attribute__((address_space(3))) void*)l, 16, 0, 0);
}

// -------- fused prep: z=0..3 transpose+cast weights, z=4..11 cast x --------
__global__ __launch_bounds__(256) void k_prep(
    const float* __restrict__ x, u16* __restrict__ xb,
    const float* __restrict__ w0, const float* __restrict__ w1,
    const float* __restrict__ w2, const float* __restrict__ w3,
    u16* __restrict__ t0, u16* __restrict__ t1,
    u16* __restrict__ t2, u16* __restrict__ t3) {
  int z = blockIdx.z;
  int tx = threadIdx.x, ty = threadIdx.y;
  if (z < 4) {
    const float* w = z == 0 ? w0 : z == 1 ? w1 : z == 2 ? w2 : w3;
    u16* t = z == 0 ? t0 : z == 1 ? t1 : z == 2 ? t2 : t3;
    __shared__ u16 tile[32][33];
    int k0 = blockIdx.x * 32, n0 = blockIdx.y * 32;
#pragma unroll
    for (int r = 0; r < 4; r++)
      tile[ty + r * 8][tx] = f2bf(w[(size_t)(k0 + ty + r * 8) * CC + n0 + tx]);
    __syncthreads();
#pragma unroll
    for (int r = 0; r < 4; r++)
      t[(size_t)(n0 + ty + r * 8) * CC + k0 + tx] = tile[tx][ty + r * 8];
  } else {
    int bid = (z - 4) * 1024 + blockIdx.y * 32 + blockIdx.x;
    int tid = ty * 32 + tx;
    int i = (bid * 256 + tid) * 4;
    float4 f = *reinterpret_cast<const float4*>(x + i);
    ushort4 o;
    o.x = f2bf(f.x); o.y = f2bf(f.y); o.z = f2bf(f.z); o.w = f2bf(f.w);
    *reinterpret_cast<ushort4*>(xb + i) = o;
  }
}

// ------------- transpose V: out_v fp32 (B,H,T,D) -> vbt bf16 (B,H,D,T) -------------
__global__ __launch_bounds__(256) void k_transpose_v(
    const float* __restrict__ out_v, u16* __restrict__ vbt) {
  int tb = blockIdx.x * 64;
  int bh = blockIdx.y;
  const float* src = out_v + (size_t)bh * TT * DD;
  u16* dst = vbt + (size_t)bh * TT * DD;
  __shared__ u16 tile[64][65];
  int tid = threadIdx.x;
#pragma unroll
  for (int p = 0; p < 4; p++) {
    int c = p * 256 + tid;
    int t = c >> 4, d0 = (c & 15) * 4;
    float4 f = *reinterpret_cast<const float4*>(src + (size_t)(tb + t) * DD + d0);
    tile[t][d0 + 0] = f2bf(f.x);
    tile[t][d0 + 1] = f2bf(f.y);
    tile[t][d0 + 2] = f2bf(f.z);
    tile[t][d0 + 3] = f2bf(f.w);
  }
  __syncthreads();
#pragma unroll
  for (int p = 0; p < 2; p++) {
    int c = p * 256 + tid;
    int d = c >> 3, t0 = (c & 7) * 8;
    ushort4 lo, hi;
    lo.x = tile[t0 + 0][d]; lo.y = tile[t0 + 1][d];
    lo.z = tile[t0 + 2][d]; lo.w = tile[t0 + 3][d];
    hi.x = tile[t0 + 4][d]; hi.y = tile[t0 + 5][d];
    hi.z = tile[t0 + 6][d]; hi.w = tile[t0 + 7][d];
    u16* o = dst + (size_t)d * TT + tb + t0;
    *reinterpret_cast<ushort4*>(o) = lo;
    *reinterpret_cast<ushort4*>(o + 4) = hi;
  }
}

// ---------------- GEMM core (R10, best measured): ring-3, 2-deep prefetch ----------------
// LDS tile [128][32] u16 (64B rows), 16B slot s of row r at linear slot
// r*4 + (s ^ ((r>>1)&3)) (R9-verified: SQ_LDS_BANK_CONFLICT = 0).
// Stage tile ks+2 at iter ks (ring-3). vmcnt(8) leaves tiles ks+1, ks+2 in
// flight and guarantees tile ks landed. Tail: vmcnt(4), vmcnt(0).
#define GEMM_PROLOGUE()                                                        \
  int tid = threadIdx.x;                                                       \
  int lane = tid & 63;                                                         \
  int wave = tid >> 6;                                                         \
  int l15 = lane & 15, quad = lane >> 4;                                       \
  int wave_m = wave & 1, wave_n = wave >> 1;                                   \
  __shared__ u16 lA[3][128 * 32];                                              \
  __shared__ u16 lB[3][128 * 32];                                              \
  f32x4 acc[4][4] = {};                                                        \
  int s_c0 = tid, s_c1 = tid + 256;                                            \
  int s_r0 = s_c0 >> 2, s_e0 = ((s_c0 & 3) ^ ((s_c0 >> 3) & 3)) * 8;           \
  int s_r1 = s_c1 >> 2, s_e1 = ((s_c1 & 3) ^ ((s_c1 >> 3) & 3)) * 8;           \
  auto gstage = [&](int buf, int k0) {                                         \
    async_copy16(A + (size_t)(tile_m + s_r0) * CC + k0 + s_e0,                 \
                 &lA[buf][s_c0 * 8]);                                          \
    async_copy16(A + (size_t)(tile_m + s_r1) * CC + k0 + s_e1,                 \
                 &lA[buf][s_c1 * 8]);                                          \
    async_copy16(Bt + (size_t)(tile_n + s_r0) * CC + k0 + s_e0,                \
                 &lB[buf][s_c0 * 8]);                                          \
    async_copy16(Bt + (size_t)(tile_n + s_r1) * CC + k0 + s_e1,                \
                 &lB[buf][s_c1 * 8]);                                          \
  };                                                                           \
  int offA[4], offB[4];                                                        \
  _Pragma("unroll")                                                            \
  for (int i = 0; i < 4; i++) {                                                \
    int rA = wave_m * 64 + i * 16 + l15;                                       \
    offA[i] = rA * 32 + (quad ^ ((rA >> 1) & 3)) * 8;                          \
    int rB = wave_n * 64 + i * 16 + l15;                                       \
    offB[i] = rB * 32 + (quad ^ ((rB >> 1) & 3)) * 8;                          \
  }                                                                            \
  gstage(0, 0);                                                                \
  gstage(1, 32);                                                               \
  int curb = 0;                                                                \
  for (int ks = 0; ks < CC / 32; ks++) {                                       \
    int nxt = curb + 2; nxt = (nxt >= 3) ? nxt - 3 : nxt;                      \
    if (ks < CC / 32 - 2) {                                                    \
      gstage(nxt, (ks + 2) * 32);                                              \
      asm volatile("s_waitcnt vmcnt(8)" ::: "memory");                         \
    } else if (ks == CC / 32 - 2) {                                            \
      asm volatile("s_waitcnt vmcnt(4)" ::: "memory");                         \
    } else {                                                                   \
      asm volatile("s_waitcnt vmcnt(0)" ::: "memory");                         \
    }                                                                          \
    __builtin_amdgcn_sched_barrier(0);                                         \
    __builtin_amdgcn_s_barrier();                                              \
    __builtin_amdgcn_sched_barrier(0);                                         \
    bf16x8 af[4], bfr[4];                                                      \
    _Pragma("unroll")                                                          \
    for (int i = 0; i < 4; i++)                                                \
      af[i] = *reinterpret_cast<const bf16x8*>(&lA[curb][offA[i]]);            \
    _Pragma("unroll")                                                          \
    for (int j = 0; j < 4; j++)                                                \
      bfr[j] = *reinterpret_cast<const bf16x8*>(&lB[curb][offB[j]]);           \
    __builtin_amdgcn_s_setprio(1);                                             \
    _Pragma("unroll")                                                          \
    for (int i = 0; i < 4; i++)                                                \
      _Pragma("unroll")                                                        \
      for (int j = 0; j < 4; j++)                                              \
        acc[i][j] =                                                            \
            __builtin_amdgcn_mfma_f32_16x16x32_bf16(af[i], bfr[j], acc[i][j],  \
                                                    0, 0, 0);                  \
    __builtin_amdgcn_s_setprio(0);                                             \
    __builtin_amdgcn_sched_barrier(0);                                         \
    __builtin_amdgcn_s_barrier();                                              \
    curb = (curb == 2) ? 0 : curb + 1;                                         \
  }

// ---------------- fused QKV GEMM ----------------
// NOTE: Q output is pre-scaled by 0.125*log2(e) so the attention kernel runs
// softmax in base-2 with no per-element scaling.
__global__ __launch_bounds__(256) void k_gemm_qkv(
    const u16* __restrict__ xb,
    const u16* __restrict__ wtq, const u16* __restrict__ wtk, const u16* __restrict__ wtv,
    const float* __restrict__ bq, const float* __restrict__ bk, const float* __restrict__ bv,
    u16* __restrict__ qb, u16* __restrict__ kb,
    float* __restrict__ out_k, float* __restrict__ out_v) {
  int mat = blockIdx.z;
  const u16* A = xb;
  const u16* Bt = mat == 0 ? wtq : mat == 1 ? wtk : wtv;
  const float* bias = mat == 0 ? bq : mat == 1 ? bk : bv;
  int tile_m = blockIdx.x * 128;
  int tile_n = blockIdx.y * 128;

  GEMM_PROLOGUE()

#pragma unroll
  for (int j = 0; j < 4; j++) {
    int n = tile_n + wave_n * 64 + j * 16 + l15;
    int h = n >> 6, d = n & 63;
    float bias_n = bias[n];
#pragma unroll
    for (int i = 0; i < 4; i++) {
#pragma unroll
      for (int r = 0; r < 4; r++) {
        int m = tile_m + wave_m * 64 + i * 16 + quad * 4 + r;
        int b = m >> 11, t = m & 2047;
        float val = acc[i][j][r] + bias_n;
        size_t idx = (((size_t)(b * HH + h)) * TT + t) * DD + d;
        if (mat == 0) {
          qb[idx] = f2bf(val * QSCALE);
        } else if (mat == 1) {
          out_k[idx] = val;
          kb[idx] = f2bf(val);
        } else {
          out_v[idx] = val;
        }
      }
    }
  }
}

// ---------------- output projection ----------------
__global__ __launch_bounds__(256) void k_gemm_proj(
    const u16* __restrict__ yb, const u16* __restrict__ wtp,
    const float* __restrict__ bp, float* __restrict__ out) {
  const u16* A = yb;
  const u16* Bt = wtp;
  int tile_m = blockIdx.x * 128;
  int tile_n = blockIdx.y * 128;

  GEMM_PROLOGUE()

#pragma unroll
  for (int j = 0; j < 4; j++) {
    int n = tile_n + wave_n * 64 + j * 16 + l15;
    float bias_n = bp[n];
#pragma unroll
    for (int i = 0; i < 4; i++) {
#pragma unroll
      for (int r = 0; r < 4; r++) {
        int m = tile_m + wave_m * 64 + i * 16 + quad * 4 + r;
        out[(size_t)m * CC + n] = acc[i][j][r] + bias_n;
      }
    }
  }
}

// ---------------- flash attention (causal), swapped QK^T + XCD-pinned heads ----------------
// R2-verified conflict-free LDS geometry (all rows 128B stride, 40 KiB).
// QK^T computed as mfma(K, Q) -> S^T (lane owns one q-row; 2-shuffle reduce);
// defer-max THR=8 (log2); base-2 softmax.
// GRID: 1-D 1024 blocks. XCD pinning (T1): linear block id n is assigned to
// XCD n%8 (round-robin); we remap so XCD g serves exactly the 8 heads with
// bh%8==g -> per-XCD K/V working set = 8 x 512KB = 4MB = its L2. Without this,
// the 16 qpair-blocks of each head spread over all 8 XCDs and every XCD
// streams ~all heads' K/V through its 4MB L2 (measured FETCH 240MB vs 67MB
// ideal). Bijective remap: bh = (n&7) | ((n>>3 & 7)<<3), qpair = n>>6.
__global__ __launch_bounds__(256) void k_attn(
    const u16* __restrict__ qb, const u16* __restrict__ kbuf,
    const u16* __restrict__ vtb, u16* __restrict__ yatt) {
  int n_blk = blockIdx.x;
  int g = n_blk & 7;
  int m_blk = n_blk >> 3;
  int bh = g | ((m_blk & 7) << 3);
  int qpair = m_blk >> 3;
  int tid = threadIdx.x;
  int lane = tid & 63;
  int wave = tid >> 6;
  int l15 = lane & 15, quad = lane >> 4;

  const u16* Q = qb + (size_t)bh * TT * DD;
  const u16* K = kbuf + (size_t)bh * TT * DD;
  const u16* Vt = vtb + (size_t)bh * TT * DD;  // [d][t]

  __shared__ u16 kl[2][64 * 64];   // swizzled [key][d], row stride 128 B
  __shared__ u16 vl[2][64 * 64];   // swizzled [d][t], row stride 128 B
  __shared__ u16 pl[4][16 * 64];   // per-wave P tile [qrow][key], swizzled
  u16* plw = pl[wave];

  int h = bh & 15, b = bh >> 4;

  int c0 = tid, c1 = tid + 256;
  int r0 = c0 >> 3, e0 = (((c0 & 7) * 16) ^ ((r0 & 7) << 4)) >> 1;
  int r1 = c1 >> 3, e1 = (((c1 & 7) * 16) ^ ((r1 & 7) << 4)) >> 1;

  auto stage = [&](int buf, int kb0) {
    async_copy16(K + (size_t)(kb0 + r0) * DD + e0, &kl[buf][c0 * 8]);
    async_copy16(K + (size_t)(kb0 + r1) * DD + e1, &kl[buf][c1 * 8]);
    async_copy16(Vt + (size_t)r0 * TT + kb0 + e0, &vl[buf][c0 * 8]);
    async_copy16(Vt + (size_t)r1 * TT + kb0 + e1, &vl[buf][c1 * 8]);
  };

  // P-write addressing (per-lane constants)
  u16* prow = plw + l15 * 64;          // this lane's q-row base
  int xrp = (l15 & 7) << 4;            // byte XOR for this row
  int q8 = quad << 3;                  // 4 contiguous keys = 8 bytes

#pragma unroll
  for (int side = 0; side < 2; side++) {
    int qt = side == 0 ? qpair : 31 - qpair;

    int qr = qt * 64 + wave * 16 + l15;
    bf16x8 qf0 = *reinterpret_cast<const bf16x8*>(Q + (size_t)qr * DD + quad * 8);
    bf16x8 qf1 = *reinterpret_cast<const bf16x8*>(Q + (size_t)qr * DD + 32 + quad * 8);

    f32x4 o_acc[4] = {};
    float m_run = -1e30f, l_run = 0.f;

    stage(0, 0);  // prologue: tile 0 into buffer 0 (4 loads/thread in flight)

    for (int kblk = 0; kblk <= qt; kblk++) {
      int cur = kblk & 1;
      if (kblk < qt) {
        stage(cur ^ 1, (kblk + 1) * 64);          // prefetch next tile
        asm volatile("s_waitcnt vmcnt(4)" ::: "memory");  // cur tile landed, next stays in flight
      } else {
        asm volatile("s_waitcnt vmcnt(0)" ::: "memory");  // last tile: drain
      }
      __builtin_amdgcn_sched_barrier(0);
      __builtin_amdgcn_s_barrier();
      __builtin_amdgcn_sched_barrier(0);

      // ---- S^T = K Q^T (64 keys x 16 qrows per wave), K from swizzled LDS ----
      f32x4 s_acc[4];
      __builtin_amdgcn_s_setprio(1);
#pragma unroll
      for (int nb = 0; nb < 4; nb++) {
        int krow = nb * 16 + l15;
        int xr = (krow & 7) << 4;
        const u16* kp = &kl[cur][krow * 64];
        bf16x8 kf0 = *reinterpret_cast<const bf16x8*>(kp + (((quad * 16) ^ xr) >> 1));
        bf16x8 kf1 = *reinterpret_cast<const bf16x8*>(kp + (((64 + quad * 16) ^ xr) >> 1));
        f32x4 z = {};
        z = __builtin_amdgcn_mfma_f32_16x16x32_bf16(kf0, qf0, z, 0, 0, 0);
        z = __builtin_amdgcn_mfma_f32_16x16x32_bf16(kf1, qf1, z, 0, 0, 0);
        s_acc[nb] = z;
      }
      __builtin_amdgcn_s_setprio(0);

      // ---- mask (diag block) + lane-local row max ----
      float mx = -1e30f;
      if (kblk == qt) {
        int qg = wave * 16 + l15;  // q offset within the 64-tile
#pragma unroll
        for (int nb = 0; nb < 4; nb++)
#pragma unroll
          for (int r = 0; r < 4; r++) {
            int kg = nb * 16 + quad * 4 + r;
            float s = s_acc[nb][r];
            s = (kg <= qg) ? s : -1e30f;
            s_acc[nb][r] = s;
            mx = fmaxf(mx, s);
          }
      } else {
#pragma unroll
        for (int nb = 0; nb < 4; nb++)
#pragma unroll
          for (int r = 0; r < 4; r++) mx = fmaxf(mx, s_acc[nb][r]);
      }
      mx = fmaxf(mx, __shfl_xor(mx, 16, 64));
      mx = fmaxf(mx, __shfl_xor(mx, 32, 64));

      // ---- defer-max: rescale only when running max grows by > 8 (log2) ----
      if (!__all(mx - m_run <= 8.0f)) {
        float mnew = fmaxf(m_run, mx);
        float alpha = __builtin_amdgcn_exp2f(m_run - mnew);
        m_run = mnew;
        l_run *= alpha;
        float av[4];
#pragma unroll
        for (int r = 0; r < 4; r++) av[r] = __shfl(alpha, quad * 4 + r, 64);
#pragma unroll
        for (int db = 0; db < 4; db++)
#pragma unroll
          for (int r = 0; r < 4; r++) o_acc[db][r] *= av[r];
      }

      // ---- exp2 + lane-local row sum (P bounded by 2^8 when deferred) ----
      float sum = 0.f;
#pragma unroll
      for (int nb = 0; nb < 4; nb++)
#pragma unroll
        for (int r = 0; r < 4; r++) {
          float e = __builtin_amdgcn_exp2f(s_acc[nb][r] - m_run);
          s_acc[nb][r] = e;
          sum += e;
        }
      sum += __shfl_xor(sum, 16, 64);
      sum += __shfl_xor(sum, 32, 64);
      l_run += sum;

      // ---- P[qrow=l15][key]: 4 contiguous keys -> one 8B store ----
#pragma unroll
      for (int nb = 0; nb < 4; nb++) {
        bf16x4 pk = {(__bf16)s_acc[nb][0], (__bf16)s_acc[nb][1],
                     (__bf16)s_acc[nb][2], (__bf16)s_acc[nb][3]};
        *reinterpret_cast<bf16x4*>(prow + ((((nb << 5) + q8) ^ xrp) >> 1)) = pk;
      }

      // ---- O += P V  (V^T from swizzled LDS) ----
      __builtin_amdgcn_s_setprio(1);
#pragma unroll
      for (int half = 0; half < 2; half++) {
        bf16x8 pf = *reinterpret_cast<const bf16x8*>(
            prow + (((half * 64 + quad * 16) ^ xrp) >> 1));
#pragma unroll
        for (int db = 0; db < 4; db++) {
          int vrow = db * 16 + l15;
          bf16x8 vf = *reinterpret_cast<const bf16x8*>(
              &vl[cur][vrow * 64] + (((half * 64 + quad * 16) ^ ((vrow & 7) << 4)) >> 1));
          o_acc[db] = __builtin_amdgcn_mfma_f32_16x16x32_bf16(pf, vf, o_acc[db], 0, 0, 0);
        }
      }
      __builtin_amdgcn_s_setprio(0);

      __builtin_amdgcn_sched_barrier(0);
      __builtin_amdgcn_s_barrier();   // all waves done reading buf cur before restage
    }

    // ---- epilogue: y_att[b][t][h*64+d] bf16 ----
    float lr[4];
#pragma unroll
    for (int r = 0; r < 4; r++) lr[r] = __shfl(l_run, quad * 4 + r, 64);
#pragma unroll
    for (int r = 0; r < 4; r++) {
      float inv = 1.0f / lr[r];
      int tq = qt * 64 + wave * 16 + quad * 4 + r;
#pragma unroll
      for (int db = 0; db < 4; db++) {
        int d = db * 16 + l15;
        yatt[((size_t)(b * TT + tq)) * CC + h * DD + d] = f2bf(o_acc[db][r] * inv);
      }
    }
  }
}

extern "C" void kernel_launch(void* const* d_in, const int* in_sizes, int n_in,
                              void* d_out, int out_size, void* d_ws, size_t ws_size,
                              hipStream_t stream) {
  const float* x  = (const float*)d_in[0];
  const float* wq = (const float*)d_in[1];
  const float* bq = (const float*)d_in[2];
  const float* wk = (const float*)d_in[3];
  const float* bk = (const float*)d_in[4];
  const float* wv = (const float*)d_in[5];
  const float* bv = (const float*)d_in[6];
  const float* wp = (const float*)d_in[7];
  const float* bp = (const float*)d_in[8];

  float* out_y = (float*)d_out;                       // (B,T,C)
  float* out_k = out_y + (size_t)BB * TT * CC;        // (B,H,T,D)
  float* out_v = out_k + (size_t)BB * HH * TT * DD;   // (B,H,T,D)

  u16* xb  = (u16*)d_ws;                    // B*T*C
  u16* wtq = xb + (size_t)BB * TT * CC;
  u16* wtk = wtq + (size_t)CC * CC;
  u16* wtv = wtk + (size_t)CC * CC;
  u16* wtp = wtv + (size_t)CC * CC;
  u16* qb  = wtp + (size_t)CC * CC;         // (B,H,T,D) bf16, pre-scaled QSCALE
  u16* kb  = qb + (size_t)BB * TT * CC;     // (B,H,T,D) bf16
  u16* vbt = kb + (size_t)BB * TT * CC;     // (B,H,D,T) bf16
  u16* yb  = vbt + (size_t)BB * TT * CC;    // (B,T,C) bf16

  k_prep<<<dim3(32, 32, 12), dim3(32, 8), 0, stream>>>(
      x, xb, wq, wk, wv, wp, wtq, wtk, wtv, wtp);
  k_gemm_qkv<<<dim3(BB * TT / 128, CC / 128, 3), 256, 0, stream>>>(
      xb, wtq, wtk, wtv, bq, bk, bv, qb, kb, out_k, out_v);
  k_transpose_v<<<dim3(TT / 64, BB * HH), 256, 0, stream>>>(out_v, vbt);
  k_attn<<<dim3(16 * BB * HH), 256, 0, stream>>>(qb, kb, vbt, yb);
  k_gemm_proj<<<dim3(BB * TT / 128, CC / 128), 256, 0, stream>>>(yb, wtp, bp, out_y);
}